// Round 1
// baseline (234.418 us; speedup 1.0000x reference)
//
#include <hip/hip_runtime.h>
#include <hip/hip_bf16.h>
#include <math.h>

#define N_ROWS 50000
#define D 128
#define K 16
#define OUT 128

// ---------------- inv_norm kernel: one wave per row ----------------
__global__ __launch_bounds__(256) void norm_kernel(const float* __restrict__ fp,
                                                   float* __restrict__ inv_norm,
                                                   int n_rows) {
    int wid = threadIdx.x >> 6;
    int lane = threadIdx.x & 63;
    int n = blockIdx.x * 4 + wid;
    if (n >= n_rows) return;
    float2 v = *reinterpret_cast<const float2*>(fp + (size_t)n * D + lane * 2);
    float s = v.x * v.x + v.y * v.y;
    #pragma unroll
    for (int off = 32; off; off >>= 1) s += __shfl_xor(s, off, 64);
    if (lane == 0) inv_norm[n] = rsqrtf(s);
}

// ---------------- GEMM kernel: Y[n][0:128] and base[n][0:128] ----------------
// Y[n][o]    = sum_d fp[n][d] * W[o][d]          (o = threadIdx.x, first 128 threads)
// base[n][o] = sum_d fp[n][d] * W[o][128+d] + b[o]  (o = threadIdx.x-128)
#define TILE_N 64
__global__ __launch_bounds__(256) void gemm_kernel(const float* __restrict__ fp,
                                                   const float* __restrict__ W,
                                                   const float* __restrict__ b,
                                                   float* __restrict__ Y,
                                                   float* __restrict__ base,
                                                   int n_rows) {
    __shared__ float lds[TILE_N * D];
    int n0 = blockIdx.x * TILE_N;
    int rows = n_rows - n0;
    if (rows > TILE_N) rows = TILE_N;
    int tid = threadIdx.x;

    // stage fp tile (rows x 128 f32) into LDS, float4 coalesced
    const float4* src = reinterpret_cast<const float4*>(fp + (size_t)n0 * D);
    float4* dstl = reinterpret_cast<float4*>(lds);
    int nvec = rows * (D / 4);
    for (int i = tid; i < nvec; i += 256) dstl[i] = src[i];
    __syncthreads();

    int c = tid;  // 0..255: col in [Y | base]
    const float* wp = (c < 128) ? (W + (size_t)c * 256) : (W + (size_t)(c - 128) * 256 + 128);
    float bias = (c < 128) ? 0.0f : b[c - 128];

    float acc[TILE_N];
    #pragma unroll
    for (int r = 0; r < TILE_N; ++r) acc[r] = 0.0f;

    for (int d = 0; d < D; d += 4) {
        float4 wv = *reinterpret_cast<const float4*>(wp + d);
        #pragma unroll
        for (int r = 0; r < TILE_N; ++r) {
            float4 f = *reinterpret_cast<const float4*>(lds + r * D + d);  // wave-uniform broadcast
            acc[r] = fmaf(f.x, wv.x, fmaf(f.y, wv.y, fmaf(f.z, wv.z, fmaf(f.w, wv.w, acc[r]))));
        }
    }

    float* dst = (c < 128) ? (Y + c) : (base + (c - 128));
    for (int r = 0; r < rows; ++r) dst[(size_t)(n0 + r) * 128] = acc[r] + bias;
}

// ---------------- main kernel: one wave per n ----------------
// out initially holds base[n][o]; each wave reads its row then overwrites it.
__global__ __launch_bounds__(256) void main_kernel(const float* __restrict__ fp,
                                                   const int* __restrict__ idx,
                                                   const float* __restrict__ Y,
                                                   const float* __restrict__ inv_norm,
                                                   float* __restrict__ out,
                                                   int n_rows) {
    int wid = threadIdx.x >> 6;
    int lane = threadIdx.x & 63;
    int n = blockIdx.x * 4 + wid;
    if (n >= n_rows) return;

    float2 fpn = *reinterpret_cast<const float2*>(fp + (size_t)n * D + lane * 2);
    float rn = inv_norm[n];
    float b0 = out[(size_t)n * 128 + lane];
    float b1 = out[(size_t)n * 128 + lane + 64];

    float a0 = -INFINITY, a1 = -INFINITY;
    #pragma unroll
    for (int k = 0; k < K; ++k) {
        int j = idx[n * K + k];
        float2 g = *reinterpret_cast<const float2*>(fp + (size_t)j * D + lane * 2);
        float p = g.x * fpn.x + g.y * fpn.y;
        #pragma unroll
        for (int off = 32; off; off >>= 1) p += __shfl_xor(p, off, 64);
        float w = p * rn * inv_norm[j];
        float y0 = Y[(size_t)j * 128 + lane];
        float y1 = Y[(size_t)j * 128 + lane + 64];
        a0 = fmaxf(a0, (y0 + b0) * w);
        a1 = fmaxf(a1, (y1 + b1) * w);
    }
    out[(size_t)n * 128 + lane] = a0;
    out[(size_t)n * 128 + lane + 64] = a1;
}

extern "C" void kernel_launch(void* const* d_in, const int* in_sizes, int n_in,
                              void* d_out, int out_size, void* d_ws, size_t ws_size,
                              hipStream_t stream) {
    const float* fp  = (const float*)d_in[0];   // (N, 128) f32
    const int*   idx = (const int*)d_in[1];     // (N, 16) int
    const float* W   = (const float*)d_in[2];   // (128, 256) f32
    const float* b   = (const float*)d_in[3];   // (128,) f32
    float* out = (float*)d_out;                 // (N, 128) f32

    float* Y = (float*)d_ws;                        // N*128 f32 = 25.6 MB
    float* inv_norm = Y + (size_t)N_ROWS * 128;     // N f32

    norm_kernel<<<(N_ROWS + 3) / 4, 256, 0, stream>>>(fp, inv_norm, N_ROWS);
    gemm_kernel<<<(N_ROWS + TILE_N - 1) / TILE_N, 256, 0, stream>>>(fp, W, b, Y, out, N_ROWS);
    main_kernel<<<(N_ROWS + 3) / 4, 256, 0, stream>>>(fp, idx, Y, inv_norm, out, N_ROWS);
}

// Round 2
// 125.241 us; speedup vs baseline: 1.8717x; 1.8717x over previous
//
#include <hip/hip_runtime.h>
#include <hip/hip_bf16.h>
#include <hip/hip_fp16.h>
#include <math.h>

#define NROWS 50000
#define D 128
#define KNB 16

typedef _Float16 f16;
typedef _Float16 f16x8 __attribute__((ext_vector_type(8)));
typedef _Float16 f16x2 __attribute__((ext_vector_type(2)));
typedef float f32x4 __attribute__((ext_vector_type(4)));

// ---- prep: fp f32 -> f16 table + inv_norm; last block converts W -> Wh(f16, [256][128]) ----
__global__ __launch_bounds__(256) void prep_kernel(const float* __restrict__ fp,
                                                   const float* __restrict__ W,
                                                   f16* __restrict__ fph,
                                                   f16* __restrict__ Wh,
                                                   float* __restrict__ inv_norm) {
    if (blockIdx.x == NROWS / 4) {
        // Wh[c][k] = c<128 ? W[c][k] : W[c-128][128+k]   (c = output col in [Y|base])
        for (int i = threadIdx.x; i < 256 * 128; i += 256) {
            int c = i >> 7, k = i & 127;
            float v = (c < 128) ? W[c * 256 + k] : W[(c - 128) * 256 + 128 + k];
            Wh[i] = (f16)v;
        }
        return;
    }
    int wid = threadIdx.x >> 6, lane = threadIdx.x & 63;
    int n = blockIdx.x * 4 + wid;
    float2 v = *reinterpret_cast<const float2*>(fp + (size_t)n * D + lane * 2);
    float s = v.x * v.x + v.y * v.y;
    #pragma unroll
    for (int off = 32; off; off >>= 1) s += __shfl_xor(s, off, 64);
    if (lane == 0) inv_norm[n] = rsqrtf(s);
    f16x2 h;
    h.x = (f16)v.x;
    h.y = (f16)v.y;
    *reinterpret_cast<f16x2*>(fph + (size_t)n * D + lane * 2) = h;
}

// ---- GEMM via MFMA: [Y_h | base] = fp @ Wcat^T ; one wave = 16 rows x 256 cols ----
__global__ __launch_bounds__(256) void gemm_kernel(const f16* __restrict__ fph,
                                                   const f16* __restrict__ Wh,
                                                   const float* __restrict__ b,
                                                   f16* __restrict__ Yh,
                                                   float* __restrict__ base) {
    int wid = threadIdx.x >> 6, lane = threadIdx.x & 63;
    int row0 = (blockIdx.x * 4 + wid) * 16;
    if (row0 >= NROWS) return;
    int r = lane & 15, kg = lane >> 4;  // A row / C col = r ; k-group = kg

    // A frags: lane holds A[r][kc*32 + kg*8 + e]
    f16x8 a[4];
    #pragma unroll
    for (int kc = 0; kc < 4; ++kc)
        a[kc] = *reinterpret_cast<const f16x8*>(fph + (size_t)(row0 + r) * D + kc * 32 + kg * 8);

    #pragma unroll
    for (int ct = 0; ct < 16; ++ct) {
        int col = ct * 16 + r;
        f32x4 acc = {0.f, 0.f, 0.f, 0.f};
        #pragma unroll
        for (int kc = 0; kc < 4; ++kc) {
            f16x8 bf = *reinterpret_cast<const f16x8*>(Wh + (size_t)col * D + kc * 32 + kg * 8);
            acc = __builtin_amdgcn_mfma_f32_16x16x32_f16(a[kc], bf, acc, 0, 0, 0);
        }
        // C/D: col = lane&15, row = row0 + kg*4 + i
        if (col < 128) {
            #pragma unroll
            for (int i = 0; i < 4; ++i)
                Yh[(size_t)(row0 + kg * 4 + i) * D + col] = (f16)acc[i];
        } else {
            float bias = b[col - 128];
            #pragma unroll
            for (int i = 0; i < 4; ++i)
                base[(size_t)(row0 + kg * 4 + i) * D + (col - 128)] = acc[i] + bias;
        }
    }
}

// ---- main: one wave per n; lane = (k = lane>>2, slice = lane&3); phase-split ----
__global__ __launch_bounds__(256) void main_kernel(const f16* __restrict__ fph,
                                                   const int* __restrict__ idx,
                                                   const f16* __restrict__ Yh,
                                                   const float* __restrict__ inv_norm,
                                                   float* __restrict__ out) {
    int wid = threadIdx.x >> 6, lane = threadIdx.x & 63;
    int n = blockIdx.x * 4 + wid;
    int s = lane & 3, k = lane >> 2;

    int j = idx[n * KNB + k];

    // phase 1: all 16 cosine dots in parallel (each lane: 32-elem slice)
    const f16x8* aj = reinterpret_cast<const f16x8*>(fph + (size_t)j * D + s * 32);
    const f16x8* an = reinterpret_cast<const f16x8*>(fph + (size_t)n * D + s * 32);
    float p = 0.f;
    #pragma unroll
    for (int q = 0; q < 4; ++q) {
        f16x8 x = aj[q], y = an[q];
        #pragma unroll
        for (int e = 0; e < 8; ++e) p += (float)x[e] * (float)y[e];
    }
    p += __shfl_xor(p, 1, 64);
    p += __shfl_xor(p, 2, 64);
    float w = p * inv_norm[n] * inv_norm[j];

    // phase 2: lane owns cols 2*lane, 2*lane+1 ; 16 independent gather+max steps
    float2 bv = *reinterpret_cast<const float2*>(out + (size_t)n * D + lane * 2);
    float a0 = -INFINITY, a1 = -INFINITY;
    #pragma unroll
    for (int kk = 0; kk < KNB; ++kk) {
        int jk = __shfl(j, kk * 4, 64);
        float wk = __shfl(w, kk * 4, 64);
        f16x2 yv = *reinterpret_cast<const f16x2*>(Yh + (size_t)jk * D + lane * 2);
        a0 = fmaxf(a0, ((float)yv.x + bv.x) * wk);
        a1 = fmaxf(a1, ((float)yv.y + bv.y) * wk);
    }
    *reinterpret_cast<float2*>(out + (size_t)n * D + lane * 2) = make_float2(a0, a1);
}

extern "C" void kernel_launch(void* const* d_in, const int* in_sizes, int n_in,
                              void* d_out, int out_size, void* d_ws, size_t ws_size,
                              hipStream_t stream) {
    const float* fp  = (const float*)d_in[0];   // (N,128) f32
    const int*   idx = (const int*)d_in[1];     // (N,16) int32
    const float* W   = (const float*)d_in[2];   // (128,256) f32
    const float* b   = (const float*)d_in[3];   // (128,) f32
    float* out = (float*)d_out;                 // (N,128) f32 ; holds base between gemm and main

    char* ws = (char*)d_ws;
    f16* fph = (f16*)ws;                                      // 12,800,000 B
    f16* Yh  = (f16*)(ws + (size_t)NROWS * D * 2);            // 12,800,000 B
    f16* Wh  = (f16*)(ws + (size_t)2 * NROWS * D * 2);        // 65,536 B
    float* inv_norm = (float*)(ws + (size_t)2 * NROWS * D * 2 + 256 * 128 * 2);  // 200,000 B

    prep_kernel<<<NROWS / 4 + 1, 256, 0, stream>>>(fp, W, fph, Wh, inv_norm);
    gemm_kernel<<<(NROWS / 16 + 3) / 4, 256, 0, stream>>>(fph, Wh, b, Yh, out);
    main_kernel<<<NROWS / 4, 256, 0, stream>>>(fph, idx, Yh, inv_norm, out);
}

// Round 3
// 82.486 us; speedup vs baseline: 2.8419x; 1.5183x over previous
//
#include <hip/hip_runtime.h>
#include <hip/hip_fp16.h>
#include <math.h>

#define NROWS 50000
#define D 128
#define KNB 16

typedef _Float16 f16;
typedef _Float16 f16x8 __attribute__((ext_vector_type(8)));
typedef _Float16 f16x2 __attribute__((ext_vector_type(2)));
typedef float f32x4 __attribute__((ext_vector_type(4)));

// ---- fused kernel: W->LDS(f16,swizzled); per wave (16 rows): fph, inv_norm, [Yh|base] ----
// 512 threads = 8 waves = 128 rows per block. LDS 64KB -> 2 blocks/CU, grid 391 all-resident.
__global__ __launch_bounds__(512) void gemm_kernel(const float* __restrict__ fp,
                                                   const float* __restrict__ W,
                                                   const float* __restrict__ b,
                                                   f16* __restrict__ fph,
                                                   f16* __restrict__ Yh,
                                                   float* __restrict__ inv_norm,
                                                   float* __restrict__ base) {
    __shared__ f16 wlds[256 * 128];  // Wcat[col][k], k chunk-swizzled: chunk ^= (col&15)
    int tid = threadIdx.x;

    // stage W (128x256 f32) -> LDS as f16 concat layout, coalesced 32B reads per thread
    #pragma unroll
    for (int it = 0; it < 8; ++it) {
        int g = tid + it * 512;          // 8-float group, 4096 total
        int i = g * 8;                   // flat index into W
        int c_w = i >> 8;                // W row (0..127)
        int kk = i & 255;                // W col (0..255)
        int destrow = (kk < 128) ? c_w : c_w + 128;
        int k = kk & 127;
        int chunk = (k >> 3) ^ (destrow & 15);
        f32x4 v0 = *(const f32x4*)(W + i);
        f32x4 v1 = *(const f32x4*)(W + i + 4);
        f16x8 h;
        #pragma unroll
        for (int e = 0; e < 4; ++e) { h[e] = (f16)v0[e]; h[4 + e] = (f16)v1[e]; }
        *(f16x8*)(wlds + destrow * 128 + chunk * 8) = h;
    }
    __syncthreads();

    int wid = tid >> 6, lane = tid & 63;
    int row0 = blockIdx.x * 128 + wid * 16;
    if (row0 >= NROWS) return;           // no barriers after this point
    int r = lane & 15, kg = lane >> 4;

    // A-frags from f32 fp, convert to f16; side-outputs fph and sum-of-squares
    f16x8 a[4];
    float ssq = 0.f;
    #pragma unroll
    for (int kc = 0; kc < 4; ++kc) {
        const float* src = fp + (size_t)(row0 + r) * D + kc * 32 + kg * 8;
        f32x4 v0 = *(const f32x4*)src;
        f32x4 v1 = *(const f32x4*)(src + 4);
        f16x8 h;
        #pragma unroll
        for (int e = 0; e < 4; ++e) {
            h[e] = (f16)v0[e];     ssq = fmaf(v0[e], v0[e], ssq);
            h[4 + e] = (f16)v1[e]; ssq = fmaf(v1[e], v1[e], ssq);
        }
        a[kc] = h;
        *(f16x8*)(fph + (size_t)(row0 + r) * D + kc * 32 + kg * 8) = h;
    }
    ssq += __shfl_xor(ssq, 16, 64);
    ssq += __shfl_xor(ssq, 32, 64);      // lanes with same r now hold full row sum
    if (kg == 0) inv_norm[row0 + r] = rsqrtf(ssq);

    #pragma unroll 4
    for (int ct = 0; ct < 16; ++ct) {
        int col = ct * 16 + r;
        f32x4 acc = {0.f, 0.f, 0.f, 0.f};
        #pragma unroll
        for (int kc = 0; kc < 4; ++kc) {
            int sc = (kc * 4 + kg) ^ r;  // swizzled chunk (matches staging XOR)
            f16x8 bf = *(const f16x8*)(wlds + col * 128 + sc * 8);
            acc = __builtin_amdgcn_mfma_f32_16x16x32_f16(a[kc], bf, acc, 0, 0, 0);
        }
        // C/D: col = lane&15 -> output channel; rows = row0 + kg*4 + i
        if (col < 128) {
            #pragma unroll
            for (int i = 0; i < 4; ++i)
                Yh[(size_t)(row0 + kg * 4 + i) * D + col] = (f16)acc[i];
        } else {
            float bias = b[col - 128];
            #pragma unroll
            for (int i = 0; i < 4; ++i)
                base[(size_t)(row0 + kg * 4 + i) * D + (col - 128)] = acc[i] + bias;
        }
    }
}

// ---- main: one wave per n; all 16 Y-gathers issued before the cosine dot ----
__global__ __launch_bounds__(256) void main_kernel(const f16* __restrict__ fph,
                                                   const int* __restrict__ idx,
                                                   const f16* __restrict__ Yh,
                                                   const float* __restrict__ inv_norm,
                                                   float* __restrict__ out) {
    int wid = threadIdx.x >> 6, lane = threadIdx.x & 63;
    int n = blockIdx.x * 4 + wid;
    int s = lane & 3, k = lane >> 2;

    int j = idx[n * KNB + k];

    // broadcast all j's; issue the full gather set up front (memory-level parallelism)
    f16x2 yv[16];
    #pragma unroll
    for (int kk = 0; kk < KNB; ++kk) {
        int jk = __shfl(j, kk * 4, 64);
        yv[kk] = *(const f16x2*)(Yh + (size_t)jk * D + lane * 2);
    }
    float2 bv = *(const float2*)(out + (size_t)n * D + lane * 2);
    float rnj = inv_norm[j];

    // cosine dot: lane = (k, 32-elem slice s); 2-shuffle reduce
    const f16x8* aj = (const f16x8*)(fph + (size_t)j * D + s * 32);
    const f16x8* an = (const f16x8*)(fph + (size_t)n * D + s * 32);
    float p = 0.f;
    #pragma unroll
    for (int q = 0; q < 4; ++q) {
        f16x8 x = aj[q], y = an[q];
        #pragma unroll
        for (int e = 0; e < 8; ++e) p += (float)x[e] * (float)y[e];
    }
    p += __shfl_xor(p, 1, 64);
    p += __shfl_xor(p, 2, 64);
    float w = p * inv_norm[n] * rnj;

    // combine: lane owns cols 2*lane, 2*lane+1
    float a0 = -INFINITY, a1 = -INFINITY;
    #pragma unroll
    for (int kk = 0; kk < KNB; ++kk) {
        float wk = __shfl(w, kk * 4, 64);
        a0 = fmaxf(a0, ((float)yv[kk].x + bv.x) * wk);
        a1 = fmaxf(a1, ((float)yv[kk].y + bv.y) * wk);
    }
    *(float2*)(out + (size_t)n * D + lane * 2) = make_float2(a0, a1);
}

extern "C" void kernel_launch(void* const* d_in, const int* in_sizes, int n_in,
                              void* d_out, int out_size, void* d_ws, size_t ws_size,
                              hipStream_t stream) {
    const float* fp  = (const float*)d_in[0];   // (N,128) f32
    const int*   idx = (const int*)d_in[1];     // (N,16) int32
    const float* W   = (const float*)d_in[2];   // (128,256) f32
    const float* b   = (const float*)d_in[3];   // (128,) f32
    float* out = (float*)d_out;                 // (N,128) f32; holds base between kernels

    char* ws = (char*)d_ws;
    f16* fph = (f16*)ws;                                   // 12.8 MB
    f16* Yh  = (f16*)(ws + (size_t)NROWS * D * 2);         // 12.8 MB
    float* inv_norm = (float*)(ws + (size_t)2 * NROWS * D * 2);  // 200 KB

    gemm_kernel<<<(NROWS + 127) / 128, 512, 0, stream>>>(fp, W, b, fph, Yh, inv_norm, out);
    main_kernel<<<NROWS / 4, 256, 0, stream>>>(fph, idx, Yh, inv_norm, out);
}